// Round 12
// baseline (121.316 us; speedup 1.0000x reference)
//
#include <hip/hip_runtime.h>

// RNNAdder round 11: r8 skeleton VERBATIM (256x256, 4 waves, packed-pair
// ring, Ca/Cb 2-deep chains, cvt-based hi/lo pack, spread projection,
// runtime-sb loop — the 56.5us baseline), with ALL data-dependent DS removed:
//  - one-hot LUT gather (random-banked b128, ~100 conflict-cy/step/CU)
//    replaced by ~25 VALU ops from a register byte (same 0x3C00 bits).
//  - per-step np b32 read replaced by pre-packed mask bytes pkm[64][33]
//    (4 steps/dword, 2-lanes-per-bank layout): 3 b32 reads per 8-step phase.

typedef _Float16 half8 __attribute__((ext_vector_type(8)));
typedef __fp16 fp16x2 __attribute__((ext_vector_type(2)));
typedef float floatx4 __attribute__((ext_vector_type(4)));
typedef int intx4 __attribute__((ext_vector_type(4)));

#define MFMA16(A, B, C) __builtin_amdgcn_mfma_f32_16x16x32_f16((A), (B), (C), 0, 0, 0)
#define BARRIER() asm volatile("s_waitcnt lgkmcnt(0)\n\ts_barrier" ::: "memory")

// pool dword layout: ring 16 slots x 16 rows x 68 dw | np scratch | pkm
#define NP_DW   17408
#define PKM_DW  19488                 // 64 x 33 dwords
#define POOL_DW 21600                 // 86.4 KB

__global__ __launch_bounds__(256)
void rnn_mfma(const int* __restrict__ num1, const int* __restrict__ num2,
              const float* __restrict__ E, const float* __restrict__ Wxh,
              const float* __restrict__ Whh, const float* __restrict__ bias,
              const float* __restrict__ Wd, const float* __restrict__ bd,
              float* __restrict__ out)
{
    __shared__ __align__(16) int pool[POOL_DW];
    int* numpk = pool + NP_DW;
    int* pkm   = pool + PKM_DW;

    const int tid  = threadIdx.x;
    const int w    = tid >> 6;
    const int lane = tid & 63;
    const int c    = lane & 15;
    const int q    = lane >> 4;
    const int qs   = q * 8;
    const int g    = blockIdx.x;

    // ---- startup staging (overlaid on ring slots 0..5) ----
    float* WhhS = (float*)pool;           // 4096
    float* P1t  = (float*)(pool + 4096);  // 640
    float* P2t  = (float*)(pool + 4736);  // 640
    float* WdS  = (float*)(pool + 5376);  // 640
    for (int i = tid; i < 4096; i += 256) WhhS[i] = Whh[i];
    for (int i = tid; i < 640;  i += 256) WdS[i]  = Wd[i];
    for (int idx = tid; idx < 640; idx += 256) {
        int v = idx >> 6, jj = idx & 63;
        float s1 = bias[jj], s2 = 0.f;
        #pragma unroll
        for (int i = 0; i < 32; ++i) {
            float e = E[v * 32 + i];
            s1 = fmaf(e, Wxh[i * 64 + jj], s1);
            s2 = fmaf(e, Wxh[(32 + i) * 64 + jj], s2);
        }
        P1t[idx] = s1;  // bias folded in
        P2t[idx] = s2;
    }
    // token bit-masks (rows 128..131 handled by guard below)
    for (int idx = tid; idx < 2080; idx += 256) {
        int m = idx & 15, t = idx >> 4;
        int s = g * 16 + m;
        numpk[t * 16 + m] = (t < 128)
            ? ((1 << num1[s * 128 + t]) | (1 << (num2[s * 128 + t] + 10))) : 0;
    }
    __syncthreads();

    // ---- pack mask bytes: pkm[l][tt] = bytes of steps 4tt..4tt+3 for lane l ----
    for (int idx = tid; idx < 64 * 33; idx += 256) {
        int l  = idx & 63;
        int tt = idx >> 6;
        int lc = l & 15, lqs = (l >> 4) * 8;
        unsigned dw = 0;
        #pragma unroll
        for (int k = 0; k < 4; ++k) {
            int t = tt * 4 + k;
            unsigned byte = (t < 128) ? ((unsigned)(numpk[t * 16 + lc] >> lqs) & 0xFFu) : 0u;
            dw |= byte << (8 * k);
        }
        pkm[l * 33 + tt] = (int)dw;
    }

    // ---- resident B-fragments (r8 verbatim) ----
    half8 Wint[4], Wdint[4], Pf;
    #pragma unroll
    for (int kt = 0; kt < 4; ++kt)
        #pragma unroll
        for (int p = 0; p < 4; ++p) {
            int k = kt * 16 + q * 4 + p;
            float wv = WhhS[k * 64 + w * 16 + c];
            Wint[kt][2 * p]     = (_Float16)wv;
            Wint[kt][2 * p + 1] = (_Float16)(wv * 0.015625f);
            float dv = (c < 10) ? WdS[k * 10 + c] : 0.f;
            Wdint[kt][2 * p]     = (_Float16)dv;
            Wdint[kt][2 * p + 1] = (_Float16)(dv * 0.015625f);
        }
    #pragma unroll
    for (int j = 0; j < 8; ++j) {
        int i2 = qs + j;
        float pv = (i2 < 10) ? P1t[i2 * 64 + w * 16 + c]
                 : (i2 < 20) ? P2t[(i2 - 10) * 64 + w * 16 + c] : 0.f;
        Pf[j] = (_Float16)pv;
    }
    float bdv = (c < 10) ? bd[c] : 0.f;
    __syncthreads();   // staging region free for ring reuse

    // ---- zero slot 15 (h_{-1}=0) ----
    for (int i = tid; i < 1088; i += 256) pool[15 * 1088 + i] = 0;
    __syncthreads();

    // ---- loop-invariant addresses (dword units) ----
    const int rBase  = c * 68 + q * 4;
    const int wBase  = (q * 4) * 68 + w * 16 + c;
    const int pkBase = lane * 33;

    float* outP[2][4];
    #pragma unroll
    for (int u = 0; u < 2; ++u)
        #pragma unroll
        for (int r = 0; r < 4; ++r)
            outP[u][r] = out + (((g * 16 + q * 4 + r) * 128) + 2 * w + u) * 10 + c;

    const floatx4 zero4 = {0.f, 0.f, 0.f, 0.f};

    // one-hot from byte (VALU only; same bit placement as the old LUT)
    #define BUILD_OH(dst, b) do {                                             \
        intx4 ohv_;                                                           \
        ohv_.x = (((b) & 1)   ? 0x3C00 : 0) | (((b) & 2)   ? 0x3C000000 : 0); \
        ohv_.y = (((b) & 4)   ? 0x3C00 : 0) | (((b) & 8)   ? 0x3C000000 : 0); \
        ohv_.z = (((b) & 16)  ? 0x3C00 : 0) | (((b) & 32)  ? 0x3C000000 : 0); \
        ohv_.w = (((b) & 64)  ? 0x3C00 : 0) | (((b) & 128) ? 0x3C000000 : 0); \
        dst = __builtin_bit_cast(half8, ohv_);                                \
    } while (0)

    // ---- prologue: Cxp for t=0 ----
    floatx4 Cxp;
    {
        unsigned b0 = (unsigned)pkm[pkBase] & 0xFFu;
        half8 Aoh;
        BUILD_OH(Aoh, b0);
        Cxp = MFMA16(Aoh, Pf, zero4);
    }

    for (int half = 0; half < 16; ++half) {
        const int sb = (half & 1) * 8;
        // phase-top mask dwords (steps half*8+1 .. half*8+8 live in tt=2h..2h+2)
        int d0 = pkm[pkBase + 2 * half];
        int d1 = pkm[pkBase + 2 * half + 1];
        int d2 = pkm[pkBase + 2 * half + 2];
        #pragma unroll
        for (int i = 0; i < 8; ++i) {
            const int spw = sb + i;
            const int spr = (i == 0) ? ((sb ^ 8) + 7) : (sb + i - 1);

            // packed A-frags: 4 x b128 (critical reads first)
            half8 A0 = *(const half8*)&pool[spr * 1088 + rBase];
            half8 A1 = *(const half8*)&pool[spr * 1088 + rBase + 16];
            half8 A2 = *(const half8*)&pool[spr * 1088 + rBase + 32];
            half8 A3 = *(const half8*)&pool[spr * 1088 + rBase + 48];

            // recurrence: hi+lo fused, 2-deep chains (r8 verbatim)
            floatx4 Ca = MFMA16(A0, Wint[0], Cxp);
            Ca         = MFMA16(A1, Wint[1], Ca);
            floatx4 Cb = MFMA16(A2, Wint[2], zero4);
            Cb         = MFMA16(A3, Wint[3], Cb);

            // next step's one-hot from register byte + xp MFMA (independent)
            {
                unsigned b = (i < 3) ? (((unsigned)d0 >> (8 * (i + 1))) & 0xFFu)
                           : (i < 7) ? (((unsigned)d1 >> (8 * (i - 3))) & 0xFFu)
                                     : ((unsigned)d2 & 0xFFu);
                half8 Aoh;
                BUILD_OH(Aoh, b);
                Cxp = MFMA16(Aoh, Pf, zero4);
            }

            // tanh + pack (hi RTN f16 | residual*64 f16) + 4 b32 writes (r8)
            float hv[4];
            #pragma unroll
            for (int r = 0; r < 4; ++r) {
                float x  = Ca[r] + Cb[r];
                float e2 = __builtin_amdgcn_exp2f(x * 2.885390081777927f);
                hv[r] = 1.f - 2.f * __builtin_amdgcn_rcpf(e2 + 1.f);
            }
            #pragma unroll
            for (int p = 0; p < 2; ++p) {
                fp16x2 ph = __builtin_amdgcn_cvt_pkrtz(hv[2 * p], hv[2 * p + 1]);
                float c0 = (float)ph[0];
                float c1 = (float)ph[1];
                fp16x2 pl = __builtin_amdgcn_cvt_pkrtz((hv[2 * p] - c0) * 64.f,
                                                       (hv[2 * p + 1] - c1) * 64.f);
                unsigned phu = __builtin_bit_cast(unsigned, ph);
                unsigned plu = __builtin_bit_cast(unsigned, pl);
                unsigned w0 = __builtin_amdgcn_perm(plu, phu, 0x05040100u);
                unsigned w1 = __builtin_amdgcn_perm(plu, phu, 0x07060302u);
                pool[spw * 1088 + wBase + (2 * p) * 68]     = (int)w0;
                pool[spw * 1088 + wBase + (2 * p + 1) * 68] = (int)w1;
            }

            // spread projection: u=0 at i==2, u=1 at i==6 (prev half's slots)
            if ((i == 2 || i == 6) && half > 0) {
                const int u   = (i == 6);
                const int sbp = (half & 1) ? 0 : 8;
                const int sl  = (sbp + 2 * w + u) * 1088 + rBase;
                half8 P0 = *(const half8*)&pool[sl];
                half8 P1 = *(const half8*)&pool[sl + 16];
                half8 P2 = *(const half8*)&pool[sl + 32];
                half8 P3 = *(const half8*)&pool[sl + 48];
                floatx4 Cp = MFMA16(P0, Wdint[0], zero4);
                Cp         = MFMA16(P1, Wdint[1], Cp);
                Cp         = MFMA16(P2, Wdint[2], Cp);
                Cp         = MFMA16(P3, Wdint[3], Cp);
                if (c < 10) {
                    #pragma unroll
                    for (int r = 0; r < 4; ++r)
                        outP[u][r][-80] = Cp[r] + bdv;
                }
            }

            BARRIER();   // lgkmcnt-only: global stores stay in flight
        }
        #pragma unroll
        for (int u = 0; u < 2; ++u)
            #pragma unroll
            for (int r = 0; r < 4; ++r)
                outP[u][r] += 80;   // +8 steps
    }
    #undef BUILD_OH

    // ---- epilogue: steps 120..127 (slots 8..15) ----
    #pragma unroll
    for (int u = 0; u < 2; ++u) {
        const int sl = (8 + 2 * w + u) * 1088 + rBase;
        half8 P0 = *(const half8*)&pool[sl];
        half8 P1 = *(const half8*)&pool[sl + 16];
        half8 P2 = *(const half8*)&pool[sl + 32];
        half8 P3 = *(const half8*)&pool[sl + 48];
        floatx4 Cp = MFMA16(P0, Wdint[0], zero4);
        Cp         = MFMA16(P1, Wdint[1], Cp);
        Cp         = MFMA16(P2, Wdint[2], Cp);
        Cp         = MFMA16(P3, Wdint[3], Cp);
        if (c < 10) {
            #pragma unroll
            for (int r = 0; r < 4; ++r)
                outP[u][r][-80] = Cp[r] + bdv;
        }
    }
}

extern "C" void kernel_launch(void* const* d_in, const int* in_sizes, int n_in,
                              void* d_out, int out_size, void* d_ws, size_t ws_size,
                              hipStream_t stream) {
    const int*   num1 = (const int*)d_in[0];
    const int*   num2 = (const int*)d_in[1];
    const float* E    = (const float*)d_in[2];
    const float* Wxh  = (const float*)d_in[3];
    const float* Whh  = (const float*)d_in[4];
    const float* b    = (const float*)d_in[5];
    const float* Wd   = (const float*)d_in[6];
    const float* bd   = (const float*)d_in[7];
    float* out = (float*)d_out;
    rnn_mfma<<<256, 256, 0, stream>>>(num1, num2, E, Wxh, Whh, b, Wd, bd, out);
}

// Round 13
// 115.127 us; speedup vs baseline: 1.0538x; 1.0538x over previous
//
#include <hip/hip_runtime.h>

// RNNAdder round 12: r8 VERBATIM recurrence + producer/consumer wave split.
// 256 WGs x 512 thr. Waves 0-3 (producers) = r8 step body (packed-pair ring,
// LUT one-hot, Ca/Cb 2-deep chains, cvt pack) MINUS the projection block.
// Waves 4-7 (consumers) hold Wd fragments and do all output projection +
// global stores, lagged one 8-step phase (slots published; producer's write
// slots disjoint from consumer's read slots; shared barrier each step).
// Consumer wave j projects timesteps 2j,2j+1 of the lagged phase at
// intervals j and j+4. Epilogue (steps 120-127) on consumers after the loop.
// All arithmetic bit-identical to r8 (56.5us) -> absmax 0.0078125.

typedef _Float16 half8 __attribute__((ext_vector_type(8)));
typedef __fp16 fp16x2 __attribute__((ext_vector_type(2)));
typedef float floatx4 __attribute__((ext_vector_type(4)));

#define MFMA16(A, B, C) __builtin_amdgcn_mfma_f32_16x16x32_f16((A), (B), (C), 0, 0, 0)
#define BARRIER() asm volatile("s_waitcnt lgkmcnt(0)\n\ts_barrier" ::: "memory")

// pool dword layout (r8): ring 16 slots x 16 rows x 68 dw | LUT | np
#define LUT_DW  17408
#define NP_DW   18432
#define POOL_DW 20512                 // 82 KB

__global__ __launch_bounds__(512)
void rnn_mfma(const int* __restrict__ num1, const int* __restrict__ num2,
              const float* __restrict__ E, const float* __restrict__ Wxh,
              const float* __restrict__ Whh, const float* __restrict__ bias,
              const float* __restrict__ Wd, const float* __restrict__ bd,
              float* __restrict__ out)
{
    __shared__ __align__(16) int pool[POOL_DW];
    int* lutI  = pool + LUT_DW;
    int* numpk = pool + NP_DW;

    const int tid  = threadIdx.x;
    const int wv   = tid >> 6;        // 0..7
    const bool prod = (wv < 4);
    const int w    = wv & 3;          // producer N-block / consumer pair id
    const int lane = tid & 63;
    const int c    = lane & 15;
    const int q    = lane >> 4;
    const int qs   = q * 8;
    const int g    = blockIdx.x;

    // ---- startup staging (overlaid on ring slots 0..5) ----
    float* WhhS = (float*)pool;           // 4096
    float* P1t  = (float*)(pool + 4096);  // 640
    float* P2t  = (float*)(pool + 4736);  // 640
    float* WdS  = (float*)(pool + 5376);  // 640
    for (int i = tid; i < 4096; i += 512) WhhS[i] = Whh[i];
    for (int i = tid; i < 640;  i += 512) WdS[i]  = Wd[i];
    for (int idx = tid; idx < 640; idx += 512) {
        int v = idx >> 6, jj = idx & 63;
        float s1 = bias[jj], s2 = 0.f;
        #pragma unroll
        for (int i = 0; i < 32; ++i) {
            float e = E[v * 32 + i];
            s1 = fmaf(e, Wxh[i * 64 + jj], s1);
            s2 = fmaf(e, Wxh[(32 + i) * 64 + jj], s2);
        }
        P1t[idx] = s1;  // bias folded in
        P2t[idx] = s2;
    }
    if (tid < 256) {   // one-hot LUT: 256 entries x 4 dw
        int e = tid;
        #pragma unroll
        for (int j = 0; j < 4; ++j)
            lutI[e * 4 + j] = (((e >> (2 * j)) & 1) ? 0x3C00 : 0)
                            | (((e >> (2 * j + 1)) & 1) ? 0x3C000000 : 0);
    }
    // token bit-masks (rows 128..129 zero-padded)
    for (int idx = tid; idx < 2080; idx += 512) {
        int m = idx & 15, t = idx >> 4;
        int s = g * 16 + m;
        numpk[t * 16 + m] = (t < 128)
            ? ((1 << num1[s * 128 + t]) | (1 << (num2[s * 128 + t] + 10))) : 0;
    }
    __syncthreads();

    // ---- per-role resident fragments ----
    half8 Wint[4], Wdint[4], Pf;
    float bdv = 0.f;
    if (prod) {
        #pragma unroll
        for (int kt = 0; kt < 4; ++kt)
            #pragma unroll
            for (int p = 0; p < 4; ++p) {
                int k = kt * 16 + q * 4 + p;
                float wvv = WhhS[k * 64 + w * 16 + c];
                Wint[kt][2 * p]     = (_Float16)wvv;
                Wint[kt][2 * p + 1] = (_Float16)(wvv * 0.015625f);
            }
        #pragma unroll
        for (int j = 0; j < 8; ++j) {
            int i2 = qs + j;
            float pv = (i2 < 10) ? P1t[i2 * 64 + w * 16 + c]
                     : (i2 < 20) ? P2t[(i2 - 10) * 64 + w * 16 + c] : 0.f;
            Pf[j] = (_Float16)pv;
        }
    } else {
        #pragma unroll
        for (int kt = 0; kt < 4; ++kt)
            #pragma unroll
            for (int p = 0; p < 4; ++p) {
                int k = kt * 16 + q * 4 + p;
                float dv = (c < 10) ? WdS[k * 10 + c] : 0.f;
                Wdint[kt][2 * p]     = (_Float16)dv;
                Wdint[kt][2 * p + 1] = (_Float16)(dv * 0.015625f);
            }
        bdv = (c < 10) ? bd[c] : 0.f;
    }
    __syncthreads();   // staging region free for ring reuse

    // ---- zero slot 15 (h_{-1}=0) ----
    for (int i = tid; i < 1088; i += 512) pool[15 * 1088 + i] = 0;
    __syncthreads();

    const int rBase = c * 68 + q * 4;
    const floatx4 zero4 = {0.f, 0.f, 0.f, 0.f};

    if (prod) {
        // ================= PRODUCER: r8 body minus projection =================
        const int wBase = (q * 4) * 68 + w * 16 + c;

        floatx4 Cxp;
        {
            int mk0 = numpk[c];
            half8 Aoh = *(const half8*)&lutI[((mk0 >> qs) & 0xFF) * 4];
            Cxp = MFMA16(Aoh, Pf, zero4);
        }

        for (int half = 0; half < 16; ++half) {
            const int sb  = (half & 1) * 8;
            const int npo = half * 128 + c;
            #pragma unroll
            for (int i = 0; i < 8; ++i) {
                int mk = numpk[npo + (i + 1) * 16];

                const int spw = sb + i;
                const int spr = (i == 0) ? ((sb ^ 8) + 7) : (sb + i - 1);

                half8 A0 = *(const half8*)&pool[spr * 1088 + rBase];
                half8 A1 = *(const half8*)&pool[spr * 1088 + rBase + 16];
                half8 A2 = *(const half8*)&pool[spr * 1088 + rBase + 32];
                half8 A3 = *(const half8*)&pool[spr * 1088 + rBase + 48];

                floatx4 Ca = MFMA16(A0, Wint[0], Cxp);
                Ca         = MFMA16(A1, Wint[1], Ca);
                floatx4 Cb = MFMA16(A2, Wint[2], zero4);
                Cb         = MFMA16(A3, Wint[3], Cb);

                {
                    int mq = (mk >> qs) & 0xFF;
                    half8 Aoh = *(const half8*)&lutI[mq * 4];
                    Cxp = MFMA16(Aoh, Pf, zero4);
                }

                float hv[4];
                #pragma unroll
                for (int r = 0; r < 4; ++r) {
                    float x  = Ca[r] + Cb[r];
                    float e2 = __builtin_amdgcn_exp2f(x * 2.885390081777927f);
                    hv[r] = 1.f - 2.f * __builtin_amdgcn_rcpf(e2 + 1.f);
                }
                #pragma unroll
                for (int p = 0; p < 2; ++p) {
                    fp16x2 ph = __builtin_amdgcn_cvt_pkrtz(hv[2 * p], hv[2 * p + 1]);
                    float c0 = (float)ph[0];
                    float c1 = (float)ph[1];
                    fp16x2 pl = __builtin_amdgcn_cvt_pkrtz((hv[2 * p] - c0) * 64.f,
                                                           (hv[2 * p + 1] - c1) * 64.f);
                    unsigned phu = __builtin_bit_cast(unsigned, ph);
                    unsigned plu = __builtin_bit_cast(unsigned, pl);
                    unsigned w0 = __builtin_amdgcn_perm(plu, phu, 0x05040100u);
                    unsigned w1 = __builtin_amdgcn_perm(plu, phu, 0x07060302u);
                    pool[spw * 1088 + wBase + (2 * p) * 68]     = (int)w0;
                    pool[spw * 1088 + wBase + (2 * p + 1) * 68] = (int)w1;
                }

                BARRIER();
            }
        }
    } else {
        // ================= CONSUMER: projection, one phase behind =============
        float* outP[2][4];
        #pragma unroll
        for (int u = 0; u < 2; ++u)
            #pragma unroll
            for (int r = 0; r < 4; ++r)
                outP[u][r] = out + (((g * 16 + q * 4 + r) * 128) + 2 * w + u) * 10 + c;
        const bool cLt10 = (c < 10);

        for (int ph = 0; ph < 16; ++ph) {
            const int sbp = (ph & 1) ? 0 : 8;   // lagged phase's slots
            #pragma unroll
            for (int i = 0; i < 8; ++i) {
                if (ph > 0 && (i == w || i == w + 4)) {
                    const int u  = (i == w) ? 0 : 1;
                    const int sl = (sbp + 2 * w + u) * 1088 + rBase;
                    half8 P0 = *(const half8*)&pool[sl];
                    half8 P1 = *(const half8*)&pool[sl + 16];
                    half8 P2 = *(const half8*)&pool[sl + 32];
                    half8 P3 = *(const half8*)&pool[sl + 48];
                    floatx4 Cp = MFMA16(P0, Wdint[0], zero4);
                    Cp         = MFMA16(P1, Wdint[1], Cp);
                    Cp         = MFMA16(P2, Wdint[2], Cp);
                    Cp         = MFMA16(P3, Wdint[3], Cp);
                    if (cLt10) {
                        #pragma unroll
                        for (int r = 0; r < 4; ++r)
                            outP[u][r][0] = Cp[r] + bdv;
                    }
                }
                BARRIER();
            }
            if (ph > 0) {
                #pragma unroll
                for (int u = 0; u < 2; ++u)
                    #pragma unroll
                    for (int r = 0; r < 4; ++r)
                        outP[u][r] += 80;   // +8 steps
            }
        }

        // epilogue: steps 120..127 (slots 8..15), after last shared barrier
        #pragma unroll
        for (int u = 0; u < 2; ++u) {
            const int sl = (8 + 2 * w + u) * 1088 + rBase;
            half8 P0 = *(const half8*)&pool[sl];
            half8 P1 = *(const half8*)&pool[sl + 16];
            half8 P2 = *(const half8*)&pool[sl + 32];
            half8 P3 = *(const half8*)&pool[sl + 48];
            floatx4 Cp = MFMA16(P0, Wdint[0], zero4);
            Cp         = MFMA16(P1, Wdint[1], Cp);
            Cp         = MFMA16(P2, Wdint[2], Cp);
            Cp         = MFMA16(P3, Wdint[3], Cp);
            if (cLt10) {
                #pragma unroll
                for (int r = 0; r < 4; ++r)
                    outP[u][r][0] = Cp[r] + bdv;
            }
        }
    }
}

extern "C" void kernel_launch(void* const* d_in, const int* in_sizes, int n_in,
                              void* d_out, int out_size, void* d_ws, size_t ws_size,
                              hipStream_t stream) {
    const int*   num1 = (const int*)d_in[0];
    const int*   num2 = (const int*)d_in[1];
    const float* E    = (const float*)d_in[2];
    const float* Wxh  = (const float*)d_in[3];
    const float* Whh  = (const float*)d_in[4];
    const float* b    = (const float*)d_in[5];
    const float* Wd   = (const float*)d_in[6];
    const float* bd   = (const float*)d_in[7];
    float* out = (float*)d_out;
    rnn_mfma<<<256, 512, 0, stream>>>(num1, num2, E, Wxh, Whh, b, Wd, bd, out);
}

// Round 14
// 112.771 us; speedup vs baseline: 1.0758x; 1.0209x over previous
//
#include <hip/hip_runtime.h>

// RNNAdder round 13: r12 (producer/consumer split, 50.5us) with DS-queue and
// chain-depth cuts:
//  (1) per-step np b32 read -> pkm packed mask bytes (3 conflict-free b32
//      reads per 8-step phase; byte from register). LUT gather KEPT (r11).
//  (2) DS order: A-reads first, LUT gather second (in-order pipe).
//  (3) recurrence = 4 independent MFMA partials + tree add (depth 1).
// All else bit-identical to r12. absmax 0.0078125 expected.

typedef _Float16 half8 __attribute__((ext_vector_type(8)));
typedef __fp16 fp16x2 __attribute__((ext_vector_type(2)));
typedef float floatx4 __attribute__((ext_vector_type(4)));

#define MFMA16(A, B, C) __builtin_amdgcn_mfma_f32_16x16x32_f16((A), (B), (C), 0, 0, 0)
#define BARRIER() asm volatile("s_waitcnt lgkmcnt(0)\n\ts_barrier" ::: "memory")

// pool dword layout: ring 16x16x68 | LUT | pkm. np scratch overlays ring
// slots 6-7 (startup only; staging uses dwords 0..6015).
#define LUT_DW  17408
#define PKM_DW  18432                 // 64 x 33 dwords
#define POOL_DW 20544                 // 82.2 KB
#define NPS_DW  6528                  // startup np scratch (ring slots 6-7)

__global__ __launch_bounds__(512)
void rnn_mfma(const int* __restrict__ num1, const int* __restrict__ num2,
              const float* __restrict__ E, const float* __restrict__ Wxh,
              const float* __restrict__ Whh, const float* __restrict__ bias,
              const float* __restrict__ Wd, const float* __restrict__ bd,
              float* __restrict__ out)
{
    __shared__ __align__(16) int pool[POOL_DW];
    int* lutI  = pool + LUT_DW;
    int* pkm   = pool + PKM_DW;
    int* npS   = pool + NPS_DW;

    const int tid  = threadIdx.x;
    const int wv   = tid >> 6;        // 0..7
    const bool prod = (wv < 4);
    const int w    = wv & 3;
    const int lane = tid & 63;
    const int c    = lane & 15;
    const int q    = lane >> 4;
    const int qs   = q * 8;
    const int g    = blockIdx.x;

    // ---- startup staging (W/P overlay dwords 0..6015; np at 6528..8607) ----
    float* WhhS = (float*)pool;           // 4096
    float* P1t  = (float*)(pool + 4096);  // 640
    float* P2t  = (float*)(pool + 4736);  // 640
    float* WdS  = (float*)(pool + 5376);  // 640
    for (int i = tid; i < 4096; i += 512) WhhS[i] = Whh[i];
    for (int i = tid; i < 640;  i += 512) WdS[i]  = Wd[i];
    for (int idx = tid; idx < 640; idx += 512) {
        int v = idx >> 6, jj = idx & 63;
        float s1 = bias[jj], s2 = 0.f;
        #pragma unroll
        for (int i = 0; i < 32; ++i) {
            float e = E[v * 32 + i];
            s1 = fmaf(e, Wxh[i * 64 + jj], s1);
            s2 = fmaf(e, Wxh[(32 + i) * 64 + jj], s2);
        }
        P1t[idx] = s1;  // bias folded in
        P2t[idx] = s2;
    }
    if (tid < 256) {   // one-hot LUT: 256 entries x 4 dw
        int e = tid;
        #pragma unroll
        for (int j = 0; j < 4; ++j)
            lutI[e * 4 + j] = (((e >> (2 * j)) & 1) ? 0x3C00 : 0)
                            | (((e >> (2 * j + 1)) & 1) ? 0x3C000000 : 0);
    }
    // token bit-masks into scratch
    for (int idx = tid; idx < 2048; idx += 512) {
        int m = idx & 15, t = idx >> 4;
        int s = g * 16 + m;
        npS[t * 16 + m] = (1 << num1[s * 128 + t]) | (1 << (num2[s * 128 + t] + 10));
    }
    __syncthreads();

    // ---- pkm: per-lane byte stream, 4 steps/dword (conflict-free stride 33) ----
    for (int idx = tid; idx < 64 * 33; idx += 512) {
        int l  = idx & 63;
        int tt = idx >> 6;
        int lc = l & 15, lqs = (l >> 4) * 8;
        unsigned dw = 0;
        #pragma unroll
        for (int k = 0; k < 4; ++k) {
            int t = tt * 4 + k;
            unsigned byte = (t < 128) ? ((unsigned)(npS[t * 16 + lc] >> lqs) & 0xFFu) : 0u;
            dw |= byte << (8 * k);
        }
        pkm[l * 33 + tt] = (int)dw;
    }

    // ---- per-role resident fragments (reads staging; disjoint from pkm) ----
    half8 Wint[4], Wdint[4], Pf;
    float bdv = 0.f;
    if (prod) {
        #pragma unroll
        for (int kt = 0; kt < 4; ++kt)
            #pragma unroll
            for (int p = 0; p < 4; ++p) {
                int k = kt * 16 + q * 4 + p;
                float wvv = WhhS[k * 64 + w * 16 + c];
                Wint[kt][2 * p]     = (_Float16)wvv;
                Wint[kt][2 * p + 1] = (_Float16)(wvv * 0.015625f);
            }
        #pragma unroll
        for (int j = 0; j < 8; ++j) {
            int i2 = qs + j;
            float pv = (i2 < 10) ? P1t[i2 * 64 + w * 16 + c]
                     : (i2 < 20) ? P2t[(i2 - 10) * 64 + w * 16 + c] : 0.f;
            Pf[j] = (_Float16)pv;
        }
    } else {
        #pragma unroll
        for (int kt = 0; kt < 4; ++kt)
            #pragma unroll
            for (int p = 0; p < 4; ++p) {
                int k = kt * 16 + q * 4 + p;
                float dv = (c < 10) ? WdS[k * 10 + c] : 0.f;
                Wdint[kt][2 * p]     = (_Float16)dv;
                Wdint[kt][2 * p + 1] = (_Float16)(dv * 0.015625f);
            }
        bdv = (c < 10) ? bd[c] : 0.f;
    }
    __syncthreads();   // staging + np scratch free for ring reuse

    // ---- zero slot 15 (h_{-1}=0) ----
    for (int i = tid; i < 1088; i += 512) pool[15 * 1088 + i] = 0;
    __syncthreads();

    const int rBase = c * 68 + q * 4;
    const floatx4 zero4 = {0.f, 0.f, 0.f, 0.f};

    if (prod) {
        // ================= PRODUCER =================
        const int wBase  = (q * 4) * 68 + w * 16 + c;
        const int pkBase = lane * 33;

        floatx4 Cxp;
        {
            unsigned b0 = (unsigned)pkm[pkBase] & 0xFFu;
            half8 Aoh = *(const half8*)&lutI[b0 * 4];
            Cxp = MFMA16(Aoh, Pf, zero4);
        }

        for (int half = 0; half < 16; ++half) {
            const int sb = (half & 1) * 8;
            int d0 = pkm[pkBase + 2 * half];
            int d1 = pkm[pkBase + 2 * half + 1];
            int d2 = pkm[pkBase + 2 * half + 2];
            #pragma unroll
            for (int i = 0; i < 8; ++i) {
                const int spw = sb + i;
                const int spr = (i == 0) ? ((sb ^ 8) + 7) : (sb + i - 1);

                // critical A-reads FIRST
                half8 A0 = *(const half8*)&pool[spr * 1088 + rBase];
                half8 A1 = *(const half8*)&pool[spr * 1088 + rBase + 16];
                half8 A2 = *(const half8*)&pool[spr * 1088 + rBase + 32];
                half8 A3 = *(const half8*)&pool[spr * 1088 + rBase + 48];
                // LUT gather second (byte from register)
                unsigned b = (i < 3) ? (((unsigned)d0 >> (8 * (i + 1))) & 0xFFu)
                           : (i < 7) ? (((unsigned)d1 >> (8 * (i - 3))) & 0xFFu)
                                     : ((unsigned)d2 & 0xFFu);
                half8 Aoh = *(const half8*)&lutI[b * 4];

                // 4 independent partials (chain depth 1)
                floatx4 Ca = MFMA16(A0, Wint[0], Cxp);
                floatx4 Cb = MFMA16(A1, Wint[1], zero4);
                floatx4 Cc = MFMA16(A2, Wint[2], zero4);
                floatx4 Cd = MFMA16(A3, Wint[3], zero4);
                // xp for t+1 (independent)
                Cxp = MFMA16(Aoh, Pf, zero4);

                float hv[4];
                #pragma unroll
                for (int r = 0; r < 4; ++r) {
                    float x  = (Ca[r] + Cb[r]) + (Cc[r] + Cd[r]);
                    float e2 = __builtin_amdgcn_exp2f(x * 2.885390081777927f);
                    hv[r] = 1.f - 2.f * __builtin_amdgcn_rcpf(e2 + 1.f);
                }
                #pragma unroll
                for (int p = 0; p < 2; ++p) {
                    fp16x2 ph = __builtin_amdgcn_cvt_pkrtz(hv[2 * p], hv[2 * p + 1]);
                    float c0 = (float)ph[0];
                    float c1 = (float)ph[1];
                    fp16x2 pl = __builtin_amdgcn_cvt_pkrtz((hv[2 * p] - c0) * 64.f,
                                                           (hv[2 * p + 1] - c1) * 64.f);
                    unsigned phu = __builtin_bit_cast(unsigned, ph);
                    unsigned plu = __builtin_bit_cast(unsigned, pl);
                    unsigned w0 = __builtin_amdgcn_perm(plu, phu, 0x05040100u);
                    unsigned w1 = __builtin_amdgcn_perm(plu, phu, 0x07060302u);
                    pool[spw * 1088 + wBase + (2 * p) * 68]     = (int)w0;
                    pool[spw * 1088 + wBase + (2 * p + 1) * 68] = (int)w1;
                }

                BARRIER();
            }
        }
    } else {
        // ================= CONSUMER: projection, one phase behind =============
        float* outP[2][4];
        #pragma unroll
        for (int u = 0; u < 2; ++u)
            #pragma unroll
            for (int r = 0; r < 4; ++r)
                outP[u][r] = out + (((g * 16 + q * 4 + r) * 128) + 2 * w + u) * 10 + c;
        const bool cLt10 = (c < 10);

        for (int ph = 0; ph < 16; ++ph) {
            const int sbp = (ph & 1) ? 0 : 8;
            #pragma unroll
            for (int i = 0; i < 8; ++i) {
                if (ph > 0 && (i == w || i == w + 4)) {
                    const int u  = (i == w) ? 0 : 1;
                    const int sl = (sbp + 2 * w + u) * 1088 + rBase;
                    half8 P0 = *(const half8*)&pool[sl];
                    half8 P1 = *(const half8*)&pool[sl + 16];
                    half8 P2 = *(const half8*)&pool[sl + 32];
                    half8 P3 = *(const half8*)&pool[sl + 48];
                    floatx4 Cp = MFMA16(P0, Wdint[0], zero4);
                    Cp         = MFMA16(P1, Wdint[1], Cp);
                    Cp         = MFMA16(P2, Wdint[2], Cp);
                    Cp         = MFMA16(P3, Wdint[3], Cp);
                    if (cLt10) {
                        #pragma unroll
                        for (int r = 0; r < 4; ++r)
                            outP[u][r][0] = Cp[r] + bdv;
                    }
                }
                BARRIER();
            }
            if (ph > 0) {
                #pragma unroll
                for (int u = 0; u < 2; ++u)
                    #pragma unroll
                    for (int r = 0; r < 4; ++r)
                        outP[u][r] += 80;
            }
        }

        // epilogue: steps 120..127 (slots 8..15)
        #pragma unroll
        for (int u = 0; u < 2; ++u) {
            const int sl = (8 + 2 * w + u) * 1088 + rBase;
            half8 P0 = *(const half8*)&pool[sl];
            half8 P1 = *(const half8*)&pool[sl + 16];
            half8 P2 = *(const half8*)&pool[sl + 32];
            half8 P3 = *(const half8*)&pool[sl + 48];
            floatx4 Cp = MFMA16(P0, Wdint[0], zero4);
            Cp         = MFMA16(P1, Wdint[1], Cp);
            Cp         = MFMA16(P2, Wdint[2], Cp);
            Cp         = MFMA16(P3, Wdint[3], Cp);
            if (cLt10) {
                #pragma unroll
                for (int r = 0; r < 4; ++r)
                    outP[u][r][0] = Cp[r] + bdv;
            }
        }
    }
}

extern "C" void kernel_launch(void* const* d_in, const int* in_sizes, int n_in,
                              void* d_out, int out_size, void* d_ws, size_t ws_size,
                              hipStream_t stream) {
    const int*   num1 = (const int*)d_in[0];
    const int*   num2 = (const int*)d_in[1];
    const float* E    = (const float*)d_in[2];
    const float* Wxh  = (const float*)d_in[3];
    const float* Whh  = (const float*)d_in[4];
    const float* b    = (const float*)d_in[5];
    const float* Wd   = (const float*)d_in[6];
    const float* bd   = (const float*)d_in[7];
    float* out = (float*)d_out;
    rnn_mfma<<<256, 512, 0, stream>>>(num1, num2, E, Wxh, Whh, b, Wd, bd, out);
}